// Round 9
// baseline (12341.238 us; speedup 1.0000x reference)
//
#include <hip/hip_runtime.h>
#include <hip/hip_bf16.h>

// Stacked 2-layer Elman RNN, B=2048 T=256 H=512 OUT=1.
//
// Round-7 lesson: depth-1 LDS staging ran at ~2700cy/group -> effective load
// latency ~5000cy because all 16 blocks/XCD sweep IDENTICAL weight addresses
// in lockstep (L2 same-line pile-up, 20% HBM leak) and only 8KB/wave was in
// flight. Sustained BW = inflight/latency, and staging caps inflight, so
// latency MUST come down. This round:
//   1) per-block kc-stagger: block b consumes kc in order (kc+koff)&15,
//      koff=(bid>>3)&15 -> the 16 blocks of an XCD pull 16 DIFFERENT weight
//      slices at any instant (K order is commutative).
//   2) 3-buffer ring, prefetch distance 2, s_waitcnt vmcnt(8): 12KB/wave
//      (96KB/CU) in flight.
//   3) clean vmcnt ledger: x preloaded to LDS BEFORE the t-loop; the loop's
//      only VMEM is global_load_lds, so the compiler inserts no drains.
// Floor: 1.5MB/step/CU @ ~270GB/s = 5.5us/step || MFMA 3.1us/step -> ~1.5ms.

typedef _Float16 half8 __attribute__((ext_vector_type(8)));
typedef float f32x4 __attribute__((ext_vector_type(4)));

#define T_STEPS 256
#define H_DIM   512
#define BM      16

#define AS1 __attribute__((address_space(1)))
#define AS3 __attribute__((address_space(3)))

#define VMW8 asm volatile("s_waitcnt vmcnt(8)" ::: "memory")
#define VMW0 asm volatile("s_waitcnt vmcnt(0)" ::: "memory")
#define BARRIER() do { \
    asm volatile("s_waitcnt lgkmcnt(0)" ::: "memory"); \
    __builtin_amdgcn_s_barrier(); \
    asm volatile("" ::: "memory"); \
  } while (0)

__device__ __forceinline__ float tanh_fast(float z){
  float az = fabsf(z);
  float e  = __expf(-2.0f * az);
  float r  = (1.0f - e) * __builtin_amdgcn_rcpf(1.0f + e);
  return copysignf(r, z);
}

// fp32 [k][n] -> fp16 MFMA-B fragments: out[(nt*16+kc)*64+lane] = 8 halves,
// col = nt*16 + (lane&15), k = kc*32 + (lane>>4)*8 + j
__global__ void prep_w_45028437131357(const float* __restrict__ W,
                                      half8* __restrict__ out){
  int tid  = blockIdx.x * 256 + threadIdx.x;
  int lane = tid & 63;
  int kc   = (tid >> 6) & 15;
  int nt   = tid >> 10;
  int col  = nt * 16 + (lane & 15);
  int k0   = kc * 32 + (lane >> 4) * 8;
  half8 v;
#pragma unroll
  for (int j = 0; j < 8; ++j) v[j] = (_Float16)W[(k0 + j) * H_DIM + col];
  out[tid] = v;
}

// stage group g (g in [0,50), wraps at 48): matrix = (g%48)>>4, kc-slot =
// ((g%48)&15 + koff)&15, ring buffer = g%3 (48%3==0 -> t-invariant).
__device__ __forceinline__ void stage_g(int g, int koff, const half8* W0,
                                        const half8* W1, const half8* WX,
                                        char* Sw, int w4, int lane){
  int g48 = (g >= 48) ? g - 48 : g;            // constant-folds after unroll
  const half8* M = (g48 < 16) ? W0 : ((g48 < 32) ? W1 : WX);
  int keff = ((g48 & 15) + koff) & 15;
  char* dst = Sw + (g % 3) * 4096;
#pragma unroll
  for (int i = 0; i < 4; ++i)
    __builtin_amdgcn_global_load_lds(
        (const AS1 void*)(M + ((w4 + i) * 16 + keff) * 64 + lane),
        (AS3 void*)(dst + i * 1024), 16, 0, 0);
}

// LDS h layout: element (row, c) at byte  row*1024 + ((c*2) ^ ((row&7)<<4))

__global__ __launch_bounds__(512, 2)
void rnn_main_45028437131357(const float* __restrict__ x,
                             const float* __restrict__ Wx0,
                             const float* __restrict__ bx0,
                             const float* __restrict__ bh0,
                             const float* __restrict__ bx1,
                             const float* __restrict__ bh1,
                             const float* __restrict__ Wfc,
                             const float* __restrict__ bfc,
                             const half8* __restrict__ Wh0f,
                             const half8* __restrict__ Wx1f,
                             const half8* __restrict__ Wh1f,
                             float* __restrict__ out){
  __shared__ __align__(16) char  h0s[BM * 1024];       // 16 KB
  __shared__ __align__(16) char  h1s[BM * 1024];       // 16 KB
  __shared__ __align__(16) float xall[BM * 256];       // 16 KB, swizzled
  __shared__ __align__(16) char  Ss[8 * 3 * 4096];     // 96 KB staging ring

  const int tid  = threadIdx.x;
  const int lane = tid & 63;
  const int w    = tid >> 6;            // 0..7, owns n-tiles 4w..4w+3
  const int w4   = 4 * w;
  const int r0   = blockIdx.x * BM;
  const int koff = (blockIdx.x >> 3) & 15;   // kc-stagger within each XCD
  char* Sw = Ss + w * 12288;            // wave-private 3-buffer ring

  // zero initial hidden state + preload x block (16 rows x 256 t) into LDS
  for (int i = tid; i < BM * 256; i += 512){
    ((float*)h0s)[i] = 0.0f;
    ((float*)h1s)[i] = 0.0f;
    int r = i >> 8, c = i & 255;
    xall[r * 256 + (c ^ ((r & 7) << 2))] = x[(r0 + r) * T_STEPS + c];
  }

  const int cl      = lane & 15;
  const int kg      = lane >> 4;
  const int aBase   = cl * 1024 + kg * 16;   // + keff*64, then ^aSwz
  const int aSwz    = (cl & 7) << 4;
  const int rowBase = kg * 4;

  // per-column constants for the 4 owned n-tiles
  float wx0c[4], b0c[4], b1c[4];
  int   colA[4];
#pragma unroll
  for (int i = 0; i < 4; ++i){
    int col = (w4 + i) * 16 + cl;
    colA[i] = col;
    wx0c[i] = Wx0[col];
    b0c[i]  = bx0[col] + bh0[col];
    b1c[i]  = bx1[col] + bh1[col];
  }

  // prologue: stage groups 0,1 (prefetch distance 2) — LAST vmem before loop
  stage_g(0, koff, Wh0f, Wh1f, Wx1f, Sw, w4, lane);
  stage_g(1, koff, Wh0f, Wh1f, Wx1f, Sw, w4, lane);

  const f32x4 z4 = {0.f, 0.f, 0.f, 0.f};

#define CONSUME(APTR, ACC, KC, G)                                             \
    {                                                                         \
      int keff = ((KC) + koff) & 15;                                          \
      const char* sb = Sw + ((G) % 3) * 4096;                                 \
      half8 a   = *(const half8*)((APTR) + ((aBase + keff * 64) ^ aSwz));     \
      half8 bb0 = *(const half8*)(sb +    0 + lane * 16);                     \
      half8 bb1 = *(const half8*)(sb + 1024 + lane * 16);                     \
      half8 bb2 = *(const half8*)(sb + 2048 + lane * 16);                     \
      half8 bb3 = *(const half8*)(sb + 3072 + lane * 16);                     \
      ACC[0] = __builtin_amdgcn_mfma_f32_16x16x32_f16(a, bb0, ACC[0], 0,0,0); \
      ACC[1] = __builtin_amdgcn_mfma_f32_16x16x32_f16(a, bb1, ACC[1], 0,0,0); \
      ACC[2] = __builtin_amdgcn_mfma_f32_16x16x32_f16(a, bb2, ACC[2], 0,0,0); \
      ACC[3] = __builtin_amdgcn_mfma_f32_16x16x32_f16(a, bb3, ACC[3], 0,0,0); \
    }

  for (int t = 0; t < T_STEPS; ++t){
    BARRIER();                            // B0: h1_new(t-1) / init visible

    f32x4 acc0[4] = {z4, z4, z4, z4};
    f32x4 acc1[4] = {z4, z4, z4, z4};

    // ---- sub-phase A0: acc0 += h0_old @ Wh0 (groups 0..15) ----
#pragma unroll
    for (int kc = 0; kc < 16; ++kc){
      stage_g(kc + 2, koff, Wh0f, Wh1f, Wx1f, Sw, w4, lane);
      VMW8;
      CONSUME(h0s, acc0, kc, kc);
    }
    // ---- sub-phase A1: acc1 += h1_old @ Wh1 (groups 16..31) ----
#pragma unroll
    for (int kc = 0; kc < 16; ++kc){
      stage_g(18 + kc, koff, Wh0f, Wh1f, Wx1f, Sw, w4, lane);
      VMW8;
      CONSUME(h1s, acc1, kc, 16 + kc);
    }

    // epilogue0: nh0 = tanh(acc0 + b0 + x*wx0)  (registers only)
    _Float16 nh0[4][4];
    {
      float xv[4];
#pragma unroll
      for (int rg = 0; rg < 4; ++rg){
        int row = rowBase + rg;
        xv[rg] = xall[row * 256 + (t ^ ((row & 7) << 2))];
      }
#pragma unroll
      for (int i = 0; i < 4; ++i)
#pragma unroll
        for (int rg = 0; rg < 4; ++rg)
          nh0[i][rg] = (_Float16)tanh_fast(acc0[i][rg] + b0c[i] + xv[rg] * wx0c[i]);
    }
    BARRIER();                            // B1: all h0/h1 reads done
#pragma unroll
    for (int i = 0; i < 4; ++i)
#pragma unroll
      for (int rg = 0; rg < 4; ++rg){
        int row = rowBase + rg;
        *(_Float16*)(h0s + row * 1024 +
                     ((colA[i] * 2) ^ ((row & 7) << 4))) = nh0[i][rg];
      }
    BARRIER();                            // B2: h0_new visible

    // ---- sub-phase B: acc1 += h0_new @ Wx1 (groups 32..47) ----
#pragma unroll
    for (int kc = 0; kc < 16; ++kc){
      stage_g(34 + kc, koff, Wh0f, Wh1f, Wx1f, Sw, w4, lane);  // 48,49 wrap
      VMW8;
      CONSUME(h0s, acc1, kc, 32 + kc);
    }

    // epilogue1: h1_new = tanh(acc1 + b1) -> h1s (visible after next B0)
#pragma unroll
    for (int i = 0; i < 4; ++i)
#pragma unroll
      for (int rg = 0; rg < 4; ++rg){
        int row = rowBase + rg;
        *(_Float16*)(h1s + row * 1024 +
                     ((colA[i] * 2) ^ ((row & 7) << 4))) =
            (_Float16)tanh_fast(acc1[i][rg] + b1c[i]);
      }
  }
#undef CONSUME
  VMW0;                                   // drain wrapped prefetches
  BARRIER();

  // ---- final FC: out[r] = h1[r,:] . Wfc + bfc ----
  {
    int r  = tid >> 5;        // 0..15
    int g2 = tid & 31;
    float p = 0.0f;
#pragma unroll
    for (int k2 = 0; k2 < 16; ++k2){
      int c = g2 + 32 * k2;
      float hv = (float)*(const _Float16*)(h1s + r * 1024 +
                                           ((c * 2) ^ ((r & 7) << 4)));
      p += hv * Wfc[c];
    }
#pragma unroll
    for (int off = 16; off >= 1; off >>= 1) p += __shfl_xor(p, off);
    if (g2 == 0) out[r0 + r] = p + bfc[0];
  }
}

extern "C" void kernel_launch(void* const* d_in, const int* in_sizes, int n_in,
                              void* d_out, int out_size, void* d_ws, size_t ws_size,
                              hipStream_t stream) {
  const float* x   = (const float*)d_in[0];
  const float* Wx0 = (const float*)d_in[1];
  const float* bx0 = (const float*)d_in[2];
  const float* Wh0 = (const float*)d_in[3];
  const float* bh0 = (const float*)d_in[4];
  const float* Wx1 = (const float*)d_in[5];
  const float* bx1 = (const float*)d_in[6];
  const float* Wh1 = (const float*)d_in[7];
  const float* bh1 = (const float*)d_in[8];
  const float* Wfc = (const float*)d_in[9];
  const float* bfc = (const float*)d_in[10];

  _Float16* wsH = (_Float16*)d_ws;
  half8* Wh0f = (half8*)(wsH);
  half8* Wx1f = (half8*)(wsH + 262144);
  half8* Wh1f = (half8*)(wsH + 524288);

  prep_w_45028437131357<<<128, 256, 0, stream>>>(Wh0, Wh0f);
  prep_w_45028437131357<<<128, 256, 0, stream>>>(Wx1, Wx1f);
  prep_w_45028437131357<<<128, 256, 0, stream>>>(Wh1, Wh1f);

  rnn_main_45028437131357<<<128, 512, 0, stream>>>(
      x, Wx0, bx0, bh0, bx1, bh1, Wfc, bfc,
      (const half8*)Wh0f, (const half8*)Wx1f, (const half8*)Wh1f,
      (float*)d_out);
}

// Round 10
// 12328.117 us; speedup vs baseline: 1.0011x; 1.0011x over previous
//
#include <hip/hip_runtime.h>
#include <hip/hip_bf16.h>

// Stacked 2-layer Elman RNN, B=2048 T=256 H=512 OUT=1.
//
// Round-7 lesson: depth-1 LDS staging ran at ~2700cy/group -> effective load
// latency ~5000cy because all 16 blocks/XCD sweep IDENTICAL weight addresses
// in lockstep (L2 same-line pile-up, 20% HBM leak) and only 8KB/wave was in
// flight. Sustained BW = inflight/latency, and staging caps inflight, so
// latency MUST come down. This round:
//   1) per-block kc-stagger: block b consumes kc in order (kc+koff)&15,
//      koff=(bid>>3)&15 -> the 16 blocks of an XCD pull 16 DIFFERENT weight
//      slices at any instant (K order is commutative).
//   2) 3-buffer ring, prefetch distance 2, s_waitcnt vmcnt(8): 12KB/wave
//      (96KB/CU) in flight.
//   3) clean vmcnt ledger: x preloaded to LDS BEFORE the t-loop; the loop's
//      only VMEM is global_load_lds, so the compiler inserts no drains.
// Floor: 1.5MB/step/CU @ ~270GB/s = 5.5us/step || MFMA 3.1us/step -> ~1.5ms.

typedef _Float16 half8 __attribute__((ext_vector_type(8)));
typedef float f32x4 __attribute__((ext_vector_type(4)));

#define T_STEPS 256
#define H_DIM   512
#define BM      16

#define AS1 __attribute__((address_space(1)))
#define AS3 __attribute__((address_space(3)))

#define VMW8 asm volatile("s_waitcnt vmcnt(8)" ::: "memory")
#define VMW0 asm volatile("s_waitcnt vmcnt(0)" ::: "memory")
#define BARRIER() do { \
    asm volatile("s_waitcnt lgkmcnt(0)" ::: "memory"); \
    __builtin_amdgcn_s_barrier(); \
    asm volatile("" ::: "memory"); \
  } while (0)

__device__ __forceinline__ float tanh_fast(float z){
  float az = fabsf(z);
  float e  = __expf(-2.0f * az);
  float r  = (1.0f - e) * __builtin_amdgcn_rcpf(1.0f + e);
  return copysignf(r, z);
}

// fp32 [k][n] -> fp16 MFMA-B fragments: out[(nt*16+kc)*64+lane] = 8 halves,
// col = nt*16 + (lane&15), k = kc*32 + (lane>>4)*8 + j
__global__ void prep_w_45028437131357(const float* __restrict__ W,
                                      half8* __restrict__ out){
  int tid  = blockIdx.x * 256 + threadIdx.x;
  int lane = tid & 63;
  int kc   = (tid >> 6) & 15;
  int nt   = tid >> 10;
  int col  = nt * 16 + (lane & 15);
  int k0   = kc * 32 + (lane >> 4) * 8;
  half8 v;
#pragma unroll
  for (int j = 0; j < 8; ++j) v[j] = (_Float16)W[(k0 + j) * H_DIM + col];
  out[tid] = v;
}

// stage group g (g in [0,50), wraps at 48): matrix = (g%48)>>4, kc-slot =
// ((g%48)&15 + koff)&15, ring buffer = g%3 (48%3==0 -> t-invariant).
__device__ __forceinline__ void stage_g(int g, int koff, const half8* W0,
                                        const half8* W1, const half8* WX,
                                        char* Sw, int w4, int lane){
  int g48 = (g >= 48) ? g - 48 : g;            // constant-folds after unroll
  const half8* M = (g48 < 16) ? W0 : ((g48 < 32) ? W1 : WX);
  int keff = ((g48 & 15) + koff) & 15;
  char* dst = Sw + (g % 3) * 4096;
#pragma unroll
  for (int i = 0; i < 4; ++i)
    __builtin_amdgcn_global_load_lds(
        (const AS1 void*)(M + ((w4 + i) * 16 + keff) * 64 + lane),
        (AS3 void*)(dst + i * 1024), 16, 0, 0);
}

// LDS h layout: element (row, c) at byte  row*1024 + ((c*2) ^ ((row&7)<<4))

__global__ __launch_bounds__(512, 2)
void rnn_main_45028437131357(const float* __restrict__ x,
                             const float* __restrict__ Wx0,
                             const float* __restrict__ bx0,
                             const float* __restrict__ bh0,
                             const float* __restrict__ bx1,
                             const float* __restrict__ bh1,
                             const float* __restrict__ Wfc,
                             const float* __restrict__ bfc,
                             const half8* __restrict__ Wh0f,
                             const half8* __restrict__ Wx1f,
                             const half8* __restrict__ Wh1f,
                             float* __restrict__ out){
  __shared__ __align__(16) char  h0s[BM * 1024];       // 16 KB
  __shared__ __align__(16) char  h1s[BM * 1024];       // 16 KB
  __shared__ __align__(16) float xall[BM * 256];       // 16 KB, swizzled
  __shared__ __align__(16) char  Ss[8 * 3 * 4096];     // 96 KB staging ring

  const int tid  = threadIdx.x;
  const int lane = tid & 63;
  const int w    = tid >> 6;            // 0..7, owns n-tiles 4w..4w+3
  const int w4   = 4 * w;
  const int r0   = blockIdx.x * BM;
  const int koff = (blockIdx.x >> 3) & 15;   // kc-stagger within each XCD
  char* Sw = Ss + w * 12288;            // wave-private 3-buffer ring

  // zero initial hidden state + preload x block (16 rows x 256 t) into LDS
  for (int i = tid; i < BM * 256; i += 512){
    ((float*)h0s)[i] = 0.0f;
    ((float*)h1s)[i] = 0.0f;
    int r = i >> 8, c = i & 255;
    xall[r * 256 + (c ^ ((r & 7) << 2))] = x[(r0 + r) * T_STEPS + c];
  }

  const int cl      = lane & 15;
  const int kg      = lane >> 4;
  const int aBase   = cl * 1024 + kg * 16;   // + keff*64, then ^aSwz
  const int aSwz    = (cl & 7) << 4;
  const int rowBase = kg * 4;

  // per-column constants for the 4 owned n-tiles
  float wx0c[4], b0c[4], b1c[4];
  int   colA[4];
#pragma unroll
  for (int i = 0; i < 4; ++i){
    int col = (w4 + i) * 16 + cl;
    colA[i] = col;
    wx0c[i] = Wx0[col];
    b0c[i]  = bx0[col] + bh0[col];
    b1c[i]  = bx1[col] + bh1[col];
  }

  // prologue: stage groups 0,1 (prefetch distance 2) — LAST vmem before loop
  stage_g(0, koff, Wh0f, Wh1f, Wx1f, Sw, w4, lane);
  stage_g(1, koff, Wh0f, Wh1f, Wx1f, Sw, w4, lane);

  const f32x4 z4 = {0.f, 0.f, 0.f, 0.f};

#define CONSUME(APTR, ACC, KC, G)                                             \
    {                                                                         \
      int keff = ((KC) + koff) & 15;                                          \
      const char* sb = Sw + ((G) % 3) * 4096;                                 \
      half8 a   = *(const half8*)((APTR) + ((aBase + keff * 64) ^ aSwz));     \
      half8 bb0 = *(const half8*)(sb +    0 + lane * 16);                     \
      half8 bb1 = *(const half8*)(sb + 1024 + lane * 16);                     \
      half8 bb2 = *(const half8*)(sb + 2048 + lane * 16);                     \
      half8 bb3 = *(const half8*)(sb + 3072 + lane * 16);                     \
      ACC[0] = __builtin_amdgcn_mfma_f32_16x16x32_f16(a, bb0, ACC[0], 0,0,0); \
      ACC[1] = __builtin_amdgcn_mfma_f32_16x16x32_f16(a, bb1, ACC[1], 0,0,0); \
      ACC[2] = __builtin_amdgcn_mfma_f32_16x16x32_f16(a, bb2, ACC[2], 0,0,0); \
      ACC[3] = __builtin_amdgcn_mfma_f32_16x16x32_f16(a, bb3, ACC[3], 0,0,0); \
    }

  for (int t = 0; t < T_STEPS; ++t){
    BARRIER();                            // B0: h1_new(t-1) / init visible

    f32x4 acc0[4] = {z4, z4, z4, z4};
    f32x4 acc1[4] = {z4, z4, z4, z4};

    // ---- sub-phase A0: acc0 += h0_old @ Wh0 (groups 0..15) ----
#pragma unroll
    for (int kc = 0; kc < 16; ++kc){
      stage_g(kc + 2, koff, Wh0f, Wh1f, Wx1f, Sw, w4, lane);
      VMW8;
      CONSUME(h0s, acc0, kc, kc);
    }
    // ---- sub-phase A1: acc1 += h1_old @ Wh1 (groups 16..31) ----
#pragma unroll
    for (int kc = 0; kc < 16; ++kc){
      stage_g(18 + kc, koff, Wh0f, Wh1f, Wx1f, Sw, w4, lane);
      VMW8;
      CONSUME(h1s, acc1, kc, 16 + kc);
    }

    // epilogue0: nh0 = tanh(acc0 + b0 + x*wx0)  (registers only)
    _Float16 nh0[4][4];
    {
      float xv[4];
#pragma unroll
      for (int rg = 0; rg < 4; ++rg){
        int row = rowBase + rg;
        xv[rg] = xall[row * 256 + (t ^ ((row & 7) << 2))];
      }
#pragma unroll
      for (int i = 0; i < 4; ++i)
#pragma unroll
        for (int rg = 0; rg < 4; ++rg)
          nh0[i][rg] = (_Float16)tanh_fast(acc0[i][rg] + b0c[i] + xv[rg] * wx0c[i]);
    }
    BARRIER();                            // B1: all h0/h1 reads done
#pragma unroll
    for (int i = 0; i < 4; ++i)
#pragma unroll
      for (int rg = 0; rg < 4; ++rg){
        int row = rowBase + rg;
        *(_Float16*)(h0s + row * 1024 +
                     ((colA[i] * 2) ^ ((row & 7) << 4))) = nh0[i][rg];
      }
    BARRIER();                            // B2: h0_new visible

    // ---- sub-phase B: acc1 += h0_new @ Wx1 (groups 32..47) ----
#pragma unroll
    for (int kc = 0; kc < 16; ++kc){
      stage_g(34 + kc, koff, Wh0f, Wh1f, Wx1f, Sw, w4, lane);  // 48,49 wrap
      VMW8;
      CONSUME(h0s, acc1, kc, 32 + kc);
    }

    // epilogue1: h1_new = tanh(acc1 + b1) -> h1s (visible after next B0)
#pragma unroll
    for (int i = 0; i < 4; ++i)
#pragma unroll
      for (int rg = 0; rg < 4; ++rg){
        int row = rowBase + rg;
        *(_Float16*)(h1s + row * 1024 +
                     ((colA[i] * 2) ^ ((row & 7) << 4))) =
            (_Float16)tanh_fast(acc1[i][rg] + b1c[i]);
      }
  }
#undef CONSUME
  VMW0;                                   // drain wrapped prefetches
  BARRIER();

  // ---- final FC: out[r] = h1[r,:] . Wfc + bfc ----
  {
    int r  = tid >> 5;        // 0..15
    int g2 = tid & 31;
    float p = 0.0f;
#pragma unroll
    for (int k2 = 0; k2 < 16; ++k2){
      int c = g2 + 32 * k2;
      float hv = (float)*(const _Float16*)(h1s + r * 1024 +
                                           ((c * 2) ^ ((r & 7) << 4)));
      p += hv * Wfc[c];
    }
#pragma unroll
    for (int off = 16; off >= 1; off >>= 1) p += __shfl_xor(p, off);
    if (g2 == 0) out[r0 + r] = p + bfc[0];
  }
}

extern "C" void kernel_launch(void* const* d_in, const int* in_sizes, int n_in,
                              void* d_out, int out_size, void* d_ws, size_t ws_size,
                              hipStream_t stream) {
  const float* x   = (const float*)d_in[0];
  const float* Wx0 = (const float*)d_in[1];
  const float* bx0 = (const float*)d_in[2];
  const float* Wh0 = (const float*)d_in[3];
  const float* bh0 = (const float*)d_in[4];
  const float* Wx1 = (const float*)d_in[5];
  const float* bx1 = (const float*)d_in[6];
  const float* Wh1 = (const float*)d_in[7];
  const float* bh1 = (const float*)d_in[8];
  const float* Wfc = (const float*)d_in[9];
  const float* bfc = (const float*)d_in[10];

  _Float16* wsH = (_Float16*)d_ws;
  half8* Wh0f = (half8*)(wsH);
  half8* Wx1f = (half8*)(wsH + 262144);
  half8* Wh1f = (half8*)(wsH + 524288);

  prep_w_45028437131357<<<128, 256, 0, stream>>>(Wh0, Wh0f);
  prep_w_45028437131357<<<128, 256, 0, stream>>>(Wx1, Wx1f);
  prep_w_45028437131357<<<128, 256, 0, stream>>>(Wh1, Wh1f);

  rnn_main_45028437131357<<<128, 512, 0, stream>>>(
      x, Wx0, bx0, bh0, bx1, bh1, Wfc, bfc,
      (const half8*)Wh0f, (const half8*)Wx1f, (const half8*)Wh1f,
      (float*)d_out);
}

// Round 11
// 12307.710 us; speedup vs baseline: 1.0027x; 1.0017x over previous
//
#include <hip/hip_runtime.h>
#include <hip/hip_bf16.h>

// Stacked 2-layer Elman RNN, B=2048 T=256 H=512 OUT=1.
//
// Round-7 lesson: depth-1 LDS staging ran at ~2700cy/group -> effective load
// latency ~5000cy because all 16 blocks/XCD sweep IDENTICAL weight addresses
// in lockstep (L2 same-line pile-up, 20% HBM leak) and only 8KB/wave was in
// flight. Sustained BW = inflight/latency, and staging caps inflight, so
// latency MUST come down. This round:
//   1) per-block kc-stagger: block b consumes kc in order (kc+koff)&15,
//      koff=(bid>>3)&15 -> the 16 blocks of an XCD pull 16 DIFFERENT weight
//      slices at any instant (K order is commutative).
//   2) 3-buffer ring, prefetch distance 2, s_waitcnt vmcnt(8): 12KB/wave
//      (96KB/CU) in flight.
//   3) clean vmcnt ledger: x preloaded to LDS BEFORE the t-loop; the loop's
//      only VMEM is global_load_lds, so the compiler inserts no drains.
// Floor: 1.5MB/step/CU @ ~270GB/s = 5.5us/step || MFMA 3.1us/step -> ~1.5ms.

typedef _Float16 half8 __attribute__((ext_vector_type(8)));
typedef float f32x4 __attribute__((ext_vector_type(4)));

#define T_STEPS 256
#define H_DIM   512
#define BM      16

#define AS1 __attribute__((address_space(1)))
#define AS3 __attribute__((address_space(3)))

#define VMW8 asm volatile("s_waitcnt vmcnt(8)" ::: "memory")
#define VMW0 asm volatile("s_waitcnt vmcnt(0)" ::: "memory")
#define BARRIER() do { \
    asm volatile("s_waitcnt lgkmcnt(0)" ::: "memory"); \
    __builtin_amdgcn_s_barrier(); \
    asm volatile("" ::: "memory"); \
  } while (0)

__device__ __forceinline__ float tanh_fast(float z){
  float az = fabsf(z);
  float e  = __expf(-2.0f * az);
  float r  = (1.0f - e) * __builtin_amdgcn_rcpf(1.0f + e);
  return copysignf(r, z);
}

// fp32 [k][n] -> fp16 MFMA-B fragments: out[(nt*16+kc)*64+lane] = 8 halves,
// col = nt*16 + (lane&15), k = kc*32 + (lane>>4)*8 + j
__global__ void prep_w_45028437131357(const float* __restrict__ W,
                                      half8* __restrict__ out){
  int tid  = blockIdx.x * 256 + threadIdx.x;
  int lane = tid & 63;
  int kc   = (tid >> 6) & 15;
  int nt   = tid >> 10;
  int col  = nt * 16 + (lane & 15);
  int k0   = kc * 32 + (lane >> 4) * 8;
  half8 v;
#pragma unroll
  for (int j = 0; j < 8; ++j) v[j] = (_Float16)W[(k0 + j) * H_DIM + col];
  out[tid] = v;
}

// stage group g (g in [0,50), wraps at 48): matrix = (g%48)>>4, kc-slot =
// ((g%48)&15 + koff)&15, ring buffer = g%3 (48%3==0 -> t-invariant).
__device__ __forceinline__ void stage_g(int g, int koff, const half8* W0,
                                        const half8* W1, const half8* WX,
                                        char* Sw, int w4, int lane){
  int g48 = (g >= 48) ? g - 48 : g;            // constant-folds after unroll
  const half8* M = (g48 < 16) ? W0 : ((g48 < 32) ? W1 : WX);
  int keff = ((g48 & 15) + koff) & 15;
  char* dst = Sw + (g % 3) * 4096;
#pragma unroll
  for (int i = 0; i < 4; ++i)
    __builtin_amdgcn_global_load_lds(
        (const AS1 void*)(M + ((w4 + i) * 16 + keff) * 64 + lane),
        (AS3 void*)(dst + i * 1024), 16, 0, 0);
}

// LDS h layout: element (row, c) at byte  row*1024 + ((c*2) ^ ((row&7)<<4))

__global__ __launch_bounds__(512, 2)
void rnn_main_45028437131357(const float* __restrict__ x,
                             const float* __restrict__ Wx0,
                             const float* __restrict__ bx0,
                             const float* __restrict__ bh0,
                             const float* __restrict__ bx1,
                             const float* __restrict__ bh1,
                             const float* __restrict__ Wfc,
                             const float* __restrict__ bfc,
                             const half8* __restrict__ Wh0f,
                             const half8* __restrict__ Wx1f,
                             const half8* __restrict__ Wh1f,
                             float* __restrict__ out){
  __shared__ __align__(16) char  h0s[BM * 1024];       // 16 KB
  __shared__ __align__(16) char  h1s[BM * 1024];       // 16 KB
  __shared__ __align__(16) float xall[BM * 256];       // 16 KB, swizzled
  __shared__ __align__(16) char  Ss[8 * 3 * 4096];     // 96 KB staging ring

  const int tid  = threadIdx.x;
  const int lane = tid & 63;
  const int w    = tid >> 6;            // 0..7, owns n-tiles 4w..4w+3
  const int w4   = 4 * w;
  const int r0   = blockIdx.x * BM;
  const int koff = (blockIdx.x >> 3) & 15;   // kc-stagger within each XCD
  char* Sw = Ss + w * 12288;            // wave-private 3-buffer ring

  // zero initial hidden state + preload x block (16 rows x 256 t) into LDS
  for (int i = tid; i < BM * 256; i += 512){
    ((float*)h0s)[i] = 0.0f;
    ((float*)h1s)[i] = 0.0f;
    int r = i >> 8, c = i & 255;
    xall[r * 256 + (c ^ ((r & 7) << 2))] = x[(r0 + r) * T_STEPS + c];
  }

  const int cl      = lane & 15;
  const int kg      = lane >> 4;
  const int aBase   = cl * 1024 + kg * 16;   // + keff*64, then ^aSwz
  const int aSwz    = (cl & 7) << 4;
  const int rowBase = kg * 4;

  // per-column constants for the 4 owned n-tiles
  float wx0c[4], b0c[4], b1c[4];
  int   colA[4];
#pragma unroll
  for (int i = 0; i < 4; ++i){
    int col = (w4 + i) * 16 + cl;
    colA[i] = col;
    wx0c[i] = Wx0[col];
    b0c[i]  = bx0[col] + bh0[col];
    b1c[i]  = bx1[col] + bh1[col];
  }

  // prologue: stage groups 0,1 (prefetch distance 2) — LAST vmem before loop
  stage_g(0, koff, Wh0f, Wh1f, Wx1f, Sw, w4, lane);
  stage_g(1, koff, Wh0f, Wh1f, Wx1f, Sw, w4, lane);

  const f32x4 z4 = {0.f, 0.f, 0.f, 0.f};

#define CONSUME(APTR, ACC, KC, G)                                             \
    {                                                                         \
      int keff = ((KC) + koff) & 15;                                          \
      const char* sb = Sw + ((G) % 3) * 4096;                                 \
      half8 a   = *(const half8*)((APTR) + ((aBase + keff * 64) ^ aSwz));     \
      half8 bb0 = *(const half8*)(sb +    0 + lane * 16);                     \
      half8 bb1 = *(const half8*)(sb + 1024 + lane * 16);                     \
      half8 bb2 = *(const half8*)(sb + 2048 + lane * 16);                     \
      half8 bb3 = *(const half8*)(sb + 3072 + lane * 16);                     \
      ACC[0] = __builtin_amdgcn_mfma_f32_16x16x32_f16(a, bb0, ACC[0], 0,0,0); \
      ACC[1] = __builtin_amdgcn_mfma_f32_16x16x32_f16(a, bb1, ACC[1], 0,0,0); \
      ACC[2] = __builtin_amdgcn_mfma_f32_16x16x32_f16(a, bb2, ACC[2], 0,0,0); \
      ACC[3] = __builtin_amdgcn_mfma_f32_16x16x32_f16(a, bb3, ACC[3], 0,0,0); \
    }

  for (int t = 0; t < T_STEPS; ++t){
    BARRIER();                            // B0: h1_new(t-1) / init visible

    f32x4 acc0[4] = {z4, z4, z4, z4};
    f32x4 acc1[4] = {z4, z4, z4, z4};

    // ---- sub-phase A0: acc0 += h0_old @ Wh0 (groups 0..15) ----
#pragma unroll
    for (int kc = 0; kc < 16; ++kc){
      stage_g(kc + 2, koff, Wh0f, Wh1f, Wx1f, Sw, w4, lane);
      VMW8;
      CONSUME(h0s, acc0, kc, kc);
    }
    // ---- sub-phase A1: acc1 += h1_old @ Wh1 (groups 16..31) ----
#pragma unroll
    for (int kc = 0; kc < 16; ++kc){
      stage_g(18 + kc, koff, Wh0f, Wh1f, Wx1f, Sw, w4, lane);
      VMW8;
      CONSUME(h1s, acc1, kc, 16 + kc);
    }

    // epilogue0: nh0 = tanh(acc0 + b0 + x*wx0)  (registers only)
    _Float16 nh0[4][4];
    {
      float xv[4];
#pragma unroll
      for (int rg = 0; rg < 4; ++rg){
        int row = rowBase + rg;
        xv[rg] = xall[row * 256 + (t ^ ((row & 7) << 2))];
      }
#pragma unroll
      for (int i = 0; i < 4; ++i)
#pragma unroll
        for (int rg = 0; rg < 4; ++rg)
          nh0[i][rg] = (_Float16)tanh_fast(acc0[i][rg] + b0c[i] + xv[rg] * wx0c[i]);
    }
    BARRIER();                            // B1: all h0/h1 reads done
#pragma unroll
    for (int i = 0; i < 4; ++i)
#pragma unroll
      for (int rg = 0; rg < 4; ++rg){
        int row = rowBase + rg;
        *(_Float16*)(h0s + row * 1024 +
                     ((colA[i] * 2) ^ ((row & 7) << 4))) = nh0[i][rg];
      }
    BARRIER();                            // B2: h0_new visible

    // ---- sub-phase B: acc1 += h0_new @ Wx1 (groups 32..47) ----
#pragma unroll
    for (int kc = 0; kc < 16; ++kc){
      stage_g(34 + kc, koff, Wh0f, Wh1f, Wx1f, Sw, w4, lane);  // 48,49 wrap
      VMW8;
      CONSUME(h0s, acc1, kc, 32 + kc);
    }

    // epilogue1: h1_new = tanh(acc1 + b1) -> h1s (visible after next B0)
#pragma unroll
    for (int i = 0; i < 4; ++i)
#pragma unroll
      for (int rg = 0; rg < 4; ++rg){
        int row = rowBase + rg;
        *(_Float16*)(h1s + row * 1024 +
                     ((colA[i] * 2) ^ ((row & 7) << 4))) =
            (_Float16)tanh_fast(acc1[i][rg] + b1c[i]);
      }
  }
#undef CONSUME
  VMW0;                                   // drain wrapped prefetches
  BARRIER();

  // ---- final FC: out[r] = h1[r,:] . Wfc + bfc ----
  {
    int r  = tid >> 5;        // 0..15
    int g2 = tid & 31;
    float p = 0.0f;
#pragma unroll
    for (int k2 = 0; k2 < 16; ++k2){
      int c = g2 + 32 * k2;
      float hv = (float)*(const _Float16*)(h1s + r * 1024 +
                                           ((c * 2) ^ ((r & 7) << 4)));
      p += hv * Wfc[c];
    }
#pragma unroll
    for (int off = 16; off >= 1; off >>= 1) p += __shfl_xor(p, off);
    if (g2 == 0) out[r0 + r] = p + bfc[0];
  }
}

extern "C" void kernel_launch(void* const* d_in, const int* in_sizes, int n_in,
                              void* d_out, int out_size, void* d_ws, size_t ws_size,
                              hipStream_t stream) {
  const float* x   = (const float*)d_in[0];
  const float* Wx0 = (const float*)d_in[1];
  const float* bx0 = (const float*)d_in[2];
  const float* Wh0 = (const float*)d_in[3];
  const float* bh0 = (const float*)d_in[4];
  const float* Wx1 = (const float*)d_in[5];
  const float* bx1 = (const float*)d_in[6];
  const float* Wh1 = (const float*)d_in[7];
  const float* bh1 = (const float*)d_in[8];
  const float* Wfc = (const float*)d_in[9];
  const float* bfc = (const float*)d_in[10];

  _Float16* wsH = (_Float16*)d_ws;
  half8* Wh0f = (half8*)(wsH);
  half8* Wx1f = (half8*)(wsH + 262144);
  half8* Wh1f = (half8*)(wsH + 524288);

  prep_w_45028437131357<<<128, 256, 0, stream>>>(Wh0, Wh0f);
  prep_w_45028437131357<<<128, 256, 0, stream>>>(Wx1, Wx1f);
  prep_w_45028437131357<<<128, 256, 0, stream>>>(Wh1, Wh1f);

  rnn_main_45028437131357<<<128, 512, 0, stream>>>(
      x, Wx0, bx0, bh0, bx1, bh1, Wfc, bfc,
      (const half8*)Wh0f, (const half8*)Wx1f, (const half8*)Wh1f,
      (float*)d_out);
}